// Round 6
// baseline (120.800 us; speedup 1.0000x reference)
//
#include <hip/hip_runtime.h>
#include <cstdint>
#include <cstddef>

typedef __attribute__((ext_vector_type(4))) int i32x4;
typedef __attribute__((ext_vector_type(4))) float f32x4;

#define XSTRIDE 848   // LDS bytes/row for xq: 53*16 -> ~2-way bank alias (free)
#define HSTRIDE 272   // LDS bytes/row for hq: 17*16
#define NT 4          // 32-row tiles per block
#define DEPTH 2       // ring depth

static __device__ __forceinline__ int q4ri(f32x4 v, float ri) {
    float a = fminf(fmaxf(rintf(v.x * ri), -127.f), 127.f);
    float b = fminf(fmaxf(rintf(v.y * ri), -127.f), 127.f);
    float c = fminf(fmaxf(rintf(v.z * ri), -127.f), 127.f);
    float d = fminf(fmaxf(rintf(v.w * ri), -127.f), 127.f);
    return ((int)a & 255) | (((int)b & 255) << 8) | (((int)c & 255) << 16) | (((int)d & 255) << 24);
}
static __device__ __forceinline__ int q4div(f32x4 v, float s) {
    float a = fminf(fmaxf(rintf(v.x / s), -127.f), 127.f);
    float b = fminf(fmaxf(rintf(v.y / s), -127.f), 127.f);
    float c = fminf(fmaxf(rintf(v.z / s), -127.f), 127.f);
    float d = fminf(fmaxf(rintf(v.w / s), -127.f), 127.f);
    return ((int)a & 255) | (((int)b & 255) << 8) | (((int)c & 255) << 16) | (((int)d & 255) << 24);
}
static __device__ __forceinline__ float max4abs(f32x4 v) {
    return fmaxf(fmaxf(fabsf(v.x), fabsf(v.y)), fmaxf(fabsf(v.z), fabsf(v.w)));
}

// spin until *f >= target (LDS flag; all lanes read same addr -> broadcast)
static __device__ __forceinline__ void spin_ge(const volatile int* f, int target) {
    while (*f < target) __builtin_amdgcn_s_sleep(2);
}

// ---------------- weight quantization (tiny, runs once per call) --------------
__global__ __launch_bounds__(64) void quantW(const float* __restrict__ W1,
                                             const float* __restrict__ W2,
                                             int8_t* __restrict__ W1q, float* __restrict__ W1s,
                                             int8_t* __restrict__ W2q, float* __restrict__ W2s) {
    const int l = threadIdx.x;
    const int b = blockIdx.x;
    if (b < 256) {
        const float* wr = W1 + (size_t)b * 784;
        f32x4 v0 = *(const f32x4*)(wr + 4 * l);
        f32x4 v1 = *(const f32x4*)(wr + 4 * (l + 64));
        f32x4 v2 = *(const f32x4*)(wr + 4 * (l + 128));
        f32x4 v3 = (f32x4){0.f, 0.f, 0.f, 0.f};
        if (l < 4) v3 = *(const f32x4*)(wr + 4 * (192 + l));
        float m = fmaxf(fmaxf(max4abs(v0), max4abs(v1)), fmaxf(max4abs(v2), max4abs(v3)));
        #pragma unroll
        for (int off = 32; off >= 1; off >>= 1) m = fmaxf(m, __shfl_xor(m, off));
        float s = (m == 0.f) ? 1.f : m / 127.f;
        int* ow = (int*)(W1q + (size_t)b * 832);
        ow[l] = q4div(v0, s);
        ow[l + 64] = q4div(v1, s);
        ow[l + 128] = q4div(v2, s);
        if (l < 4) ow[192 + l] = q4div(v3, s);
        if (l >= 16 && l < 28) ow[196 + (l - 16)] = 0;
        if (l == 0) W1s[b] = s;
    } else {
        const int r = b - 256;
        int* ow = (int*)(W2q + (size_t)r * 256);
        if (r < 10) {
            f32x4 v0 = *(const f32x4*)(W2 + (size_t)r * 256 + 4 * l);
            float m = max4abs(v0);
            #pragma unroll
            for (int off = 32; off >= 1; off >>= 1) m = fmaxf(m, __shfl_xor(m, off));
            float s = (m == 0.f) ? 1.f : m / 127.f;
            ow[l] = q4div(v0, s);
            if (l == 0) W2s[r] = s;
        } else {
            ow[l] = 0;
            if (l == 0) W2s[r] = 1.f;
        }
    }
}

// ------- fused MLP, wave-specialized producer/consumer over an LDS ring -------
// 8 waves: w0..3 produce (stream x -> absmax -> int8 into xq ring),
// w4..7 consume (GEMM1 -> relu+requant -> GEMM2 -> store). No __syncthreads
// in the pipeline; per-tile LDS counters. 2 blocks/CU (LDS ~75 KB).
__global__ __launch_bounds__(512, 4) void fused_mlp(
    const float* __restrict__ x,
    const int8_t* __restrict__ W1q, const float* __restrict__ W1s, const float* __restrict__ b1,
    const int8_t* __restrict__ W2q, const float* __restrict__ W2s, const float* __restrict__ b2,
    float* __restrict__ out)
{
    __shared__ __align__(16) int8_t xq[DEPTH][32 * XSTRIDE];   // 54272 B
    __shared__ __align__(16) int8_t hq[DEPTH][32 * HSTRIDE];   // 17408 B
    __shared__ float sxs[DEPTH][32];
    __shared__ float s2s[DEPTH][32];
    __shared__ float hpart[DEPTH][4][32];
    __shared__ float b1s[256], w1ss[256];
    __shared__ float b2s[16], w2ss[16];
    __shared__ int ready[NT];      // producers done with tile t (==4)
    __shared__ int consdone[NT];   // consumers done reading xq of tile t (==4)
    __shared__ int sync1[NT];      // consumer rendezvous after hpart
    __shared__ int sync2[NT];      // consumer rendezvous after hq/s2s

    const int t = threadIdx.x;
    const int l = t & 63;
    const int w = t >> 6;            // wave 0..7
    const int g = l >> 4;            // 16-lane group 0..3
    const int lr = l & 15;
    const size_t blk0 = (size_t)blockIdx.x * (32 * NT);

    if (t < 256) { b1s[t] = b1[t]; w1ss[t] = W1s[t]; }
    if (t >= 256 && t < 272) {
        const int i = t - 256;
        w2ss[i] = W2s[i];
        b2s[i] = (i < 10) ? b2[i] : 0.f;
    }
    if (t < NT) { ready[t] = 0; consdone[t] = 0; sync1[t] = 0; sync2[t] = 0; }
    __syncthreads();   // the only full barrier

    if (w < 4) {
        // ======================= PRODUCER =======================
        const int rbase = w * 8;     // 8 rows of each 32-row tile
        for (int tt = 0; tt < NT; ++tt) {
            const int sl = tt & 1;
            const float* xb = x + (blk0 + (size_t)tt * 32 + rbase) * 784;

            // issue row-0 loads BEFORE gating on the slot (keeps HBM busy)
            f32x4 c0 = *(const f32x4*)(xb + 4 * l);
            f32x4 c1 = *(const f32x4*)(xb + 4 * (l + 64));
            f32x4 c2 = *(const f32x4*)(xb + 4 * (l + 128));
            f32x4 c3 = (f32x4){0.f, 0.f, 0.f, 0.f};
            if (l < 4) c3 = *(const f32x4*)(xb + 4 * (192 + l));

            if (tt >= DEPTH) {
                spin_ge(&consdone[tt - DEPTH], 4);
                __threadfence_block();
            }

            #pragma unroll
            for (int r = 0; r < 8; ++r) {
                f32x4 n0, n1, n2, n3;
                if (r < 7) {
                    const float* xr = xb + (size_t)(r + 1) * 784;
                    n0 = *(const f32x4*)(xr + 4 * l);
                    n1 = *(const f32x4*)(xr + 4 * (l + 64));
                    n2 = *(const f32x4*)(xr + 4 * (l + 128));
                    n3 = (f32x4){0.f, 0.f, 0.f, 0.f};
                    if (l < 4) n3 = *(const f32x4*)(xr + 4 * (192 + l));
                }
                float m = fmaxf(fmaxf(max4abs(c0), max4abs(c1)), fmaxf(max4abs(c2), max4abs(c3)));
                #pragma unroll
                for (int off = 32; off >= 1; off >>= 1) m = fmaxf(m, __shfl_xor(m, off));
                float s = (m == 0.f) ? 1.f : m / 127.f;
                float ri = 1.f / s;
                int* xw = (int*)(xq[sl] + (rbase + r) * XSTRIDE);
                xw[l] = q4ri(c0, ri);
                xw[l + 64] = q4ri(c1, ri);
                xw[l + 128] = q4ri(c2, ri);
                if (l < 4) xw[192 + l] = q4ri(c3, ri);
                if (l >= 16 && l < 32) xw[196 + (l - 16)] = 0;   // zero K-pad
                if (l == 0) sxs[sl][rbase + r] = s;
                c0 = n0; c1 = n1; c2 = n2; c3 = n3;
            }
            __threadfence_block();
            if (l == 0) atomicAdd(&ready[tt], 1);
        }
    } else {
        // ======================= CONSUMER =======================
        const int cw = w - 4;        // 0..3
        for (int tt = 0; tt < NT; ++tt) {
            const int sl = tt & 1;
            const size_t row0 = blk0 + (size_t)tt * 32;

            spin_ge(&ready[tt], 4);
            __threadfence_block();

            // ---- GEMM1: this wave owns cols cw*64..cw*64+63, rows 0..31 ----
            i32x4 acc[2][4];
            #pragma unroll
            for (int mt = 0; mt < 2; ++mt)
                #pragma unroll
                for (int nt = 0; nt < 4; ++nt)
                    acc[mt][nt] = (i32x4){0, 0, 0, 0};

            const int8_t* xbase = xq[sl] + lr * XSTRIDE + g * 16;
            const int8_t* wbase = W1q + (size_t)(cw * 64 + lr) * 832 + g * 16;

            #pragma unroll
            for (int kk = 0; kk < 13; ++kk) {
                const int ko = kk * 64;
                i32x4 a[2], bv[4];
                #pragma unroll
                for (int mt = 0; mt < 2; ++mt) a[mt] = *(const i32x4*)(xbase + mt * 16 * XSTRIDE + ko);
                #pragma unroll
                for (int nt = 0; nt < 4; ++nt) bv[nt] = *(const i32x4*)(wbase + (size_t)nt * 16 * 832 + ko);
                #pragma unroll
                for (int mt = 0; mt < 2; ++mt)
                    #pragma unroll
                    for (int nt = 0; nt < 4; ++nt)
                        acc[mt][nt] = __builtin_amdgcn_mfma_i32_16x16x64_i8(a[mt], bv[nt], acc[mt][nt], 0, 0, 0);
            }

            // preload sxs for my 8 output rows, then release the xq slot
            float sxv[2][4];
            #pragma unroll
            for (int mt = 0; mt < 2; ++mt)
                #pragma unroll
                for (int r = 0; r < 4; ++r)
                    sxv[mt][r] = sxs[sl][mt * 16 + g * 4 + r];
            __threadfence_block();
            if (l == 0) atomicAdd(&consdone[tt], 1);

            // ---- dequant + bias + relu ----
            float h[2][4][4];
            #pragma unroll
            for (int mt = 0; mt < 2; ++mt)
                #pragma unroll
                for (int nt = 0; nt < 4; ++nt)
                    #pragma unroll
                    for (int r = 0; r < 4; ++r) {
                        const int coll = cw * 64 + nt * 16 + lr;
                        float v = sxv[mt][r] * w1ss[coll] * (float)acc[mt][nt][r] + b1s[coll];
                        h[mt][r][nt] = fmaxf(v, 0.f);
                    }

            // ---- per-row max over my 64 cols ----
            #pragma unroll
            for (int mt = 0; mt < 2; ++mt)
                #pragma unroll
                for (int r = 0; r < 4; ++r) {
                    float m = fmaxf(fmaxf(h[mt][r][0], h[mt][r][1]), fmaxf(h[mt][r][2], h[mt][r][3]));
                    m = fmaxf(m, __shfl_xor(m, 1));
                    m = fmaxf(m, __shfl_xor(m, 2));
                    m = fmaxf(m, __shfl_xor(m, 4));
                    m = fmaxf(m, __shfl_xor(m, 8));
                    if (lr == 0) hpart[sl][cw][mt * 16 + g * 4 + r] = m;
                }
            __threadfence_block();
            if (l == 0) atomicAdd(&sync1[tt], 1);
            spin_ge(&sync1[tt], 4);
            __threadfence_block();

            // ---- requantize h into hq[sl] ----
            #pragma unroll
            for (int mt = 0; mt < 2; ++mt)
                #pragma unroll
                for (int r = 0; r < 4; ++r) {
                    const int rowl = mt * 16 + g * 4 + r;
                    float hm = fmaxf(fmaxf(hpart[sl][0][rowl], hpart[sl][1][rowl]),
                                     fmaxf(hpart[sl][2][rowl], hpart[sl][3][rowl]));
                    float s2 = (hm == 0.f) ? 1.f : hm / 127.f;
                    float ri2 = 1.f / s2;
                    if (cw == 0 && lr == 0) s2s[sl][rowl] = s2;
                    #pragma unroll
                    for (int nt = 0; nt < 4; ++nt) {
                        float q = fminf(fmaxf(rintf(h[mt][r][nt] * ri2), -127.f), 127.f);
                        hq[sl][rowl * HSTRIDE + cw * 64 + nt * 16 + lr] = (int8_t)(int)q;
                    }
                }
            __threadfence_block();
            if (l == 0) atomicAdd(&sync2[tt], 1);
            spin_ge(&sync2[tt], 4);
            __threadfence_block();

            // ---- GEMM2 (consumer waves 0..1, 16 rows each) + epilogue ----
            if (cw < 2) {
                i32x4 acc2 = (i32x4){0, 0, 0, 0};
                const int8_t* hbase = hq[sl] + (cw * 16 + lr) * HSTRIDE + g * 16;
                const int8_t* w2base = W2q + lr * 256 + g * 16;
                #pragma unroll
                for (int kk = 0; kk < 4; ++kk) {
                    i32x4 av = *(const i32x4*)(hbase + kk * 64);
                    i32x4 bv = *(const i32x4*)(w2base + kk * 64);
                    acc2 = __builtin_amdgcn_mfma_i32_16x16x64_i8(av, bv, acc2, 0, 0, 0);
                }
                if (lr < 10) {
                    #pragma unroll
                    for (int r = 0; r < 4; ++r) {
                        const int rowl = cw * 16 + g * 4 + r;
                        float v = s2s[sl][rowl] * w2ss[lr] * (float)acc2[r] + b2s[lr];
                        out[(row0 + rowl) * 10 + lr] = v;
                    }
                }
            }
        }
    }
}

extern "C" void kernel_launch(void* const* d_in, const int* in_sizes, int n_in,
                              void* d_out, int out_size, void* d_ws, size_t ws_size,
                              hipStream_t stream) {
    const float* x  = (const float*)d_in[0];
    const float* W1 = (const float*)d_in[1];
    const float* b1 = (const float*)d_in[2];
    const float* W2 = (const float*)d_in[3];
    const float* b2 = (const float*)d_in[4];
    float* out = (float*)d_out;

    int8_t* ws = (int8_t*)d_ws;
    int8_t* W1q = ws;                            // 256*832   = 212992 B
    float*  W1s = (float*)(ws + 212992);         // 1024 B
    int8_t* W2q = ws + 214016;                   // 4096 B
    float*  W2s = (float*)(ws + 218112);         // 64 B

    quantW<<<272, 64, 0, stream>>>(W1, W2, W1q, W1s, W2q, W2s);
    fused_mlp<<<512, 512, 0, stream>>>(x, W1q, W1s, b1, W2q, W2s, b2, out);
}

// Round 7
// 66.211 us; speedup vs baseline: 1.8245x; 1.8245x over previous
//
#include <hip/hip_runtime.h>
#include <cstdint>
#include <cstddef>

typedef __attribute__((ext_vector_type(4))) int i32x4;
typedef __attribute__((ext_vector_type(4))) float f32x4;

#define BM 32         // rows per block -> ~39 KB LDS -> 4 blocks/CU
#define XSTRIDE 848   // LDS bytes/row for xq: stride 212 dwords -> 2-way bank alias (free)
#define HSTRIDE 272   // LDS bytes/row for hq

static __device__ __forceinline__ int q4ri(f32x4 v, float ri) {
    float a = fminf(fmaxf(rintf(v.x * ri), -127.f), 127.f);
    float b = fminf(fmaxf(rintf(v.y * ri), -127.f), 127.f);
    float c = fminf(fmaxf(rintf(v.z * ri), -127.f), 127.f);
    float d = fminf(fmaxf(rintf(v.w * ri), -127.f), 127.f);
    return ((int)a & 255) | (((int)b & 255) << 8) | (((int)c & 255) << 16) | (((int)d & 255) << 24);
}
static __device__ __forceinline__ int q4div(f32x4 v, float s) {
    float a = fminf(fmaxf(rintf(v.x / s), -127.f), 127.f);
    float b = fminf(fmaxf(rintf(v.y / s), -127.f), 127.f);
    float c = fminf(fmaxf(rintf(v.z / s), -127.f), 127.f);
    float d = fminf(fmaxf(rintf(v.w / s), -127.f), 127.f);
    return ((int)a & 255) | (((int)b & 255) << 8) | (((int)c & 255) << 16) | (((int)d & 255) << 24);
}
static __device__ __forceinline__ float max4abs(f32x4 v) {
    return fmaxf(fmaxf(fabsf(v.x), fabsf(v.y)), fmaxf(fabsf(v.z), fabsf(v.w)));
}

// ---------------- weight quantization (tiny, runs once per call) --------------
__global__ __launch_bounds__(64) void quantW(const float* __restrict__ W1,
                                             const float* __restrict__ W2,
                                             int8_t* __restrict__ W1q, float* __restrict__ W1s,
                                             int8_t* __restrict__ W2q, float* __restrict__ W2s) {
    const int l = threadIdx.x;
    const int b = blockIdx.x;
    if (b < 256) {
        const float* wr = W1 + (size_t)b * 784;
        f32x4 v0 = *(const f32x4*)(wr + 4 * l);
        f32x4 v1 = *(const f32x4*)(wr + 4 * (l + 64));
        f32x4 v2 = *(const f32x4*)(wr + 4 * (l + 128));
        f32x4 v3 = (f32x4){0.f, 0.f, 0.f, 0.f};
        if (l < 4) v3 = *(const f32x4*)(wr + 4 * (192 + l));
        float m = fmaxf(fmaxf(max4abs(v0), max4abs(v1)), fmaxf(max4abs(v2), max4abs(v3)));
        #pragma unroll
        for (int off = 32; off >= 1; off >>= 1) m = fmaxf(m, __shfl_xor(m, off));
        float s = (m == 0.f) ? 1.f : m / 127.f;
        int* ow = (int*)(W1q + (size_t)b * 832);
        ow[l] = q4div(v0, s);
        ow[l + 64] = q4div(v1, s);
        ow[l + 128] = q4div(v2, s);
        if (l < 4) ow[192 + l] = q4div(v3, s);
        if (l >= 16 && l < 28) ow[196 + (l - 16)] = 0;
        if (l == 0) W1s[b] = s;
    } else {
        const int r = b - 256;
        int* ow = (int*)(W2q + (size_t)r * 256);
        if (r < 10) {
            f32x4 v0 = *(const f32x4*)(W2 + (size_t)r * 256 + 4 * l);
            float m = max4abs(v0);
            #pragma unroll
            for (int off = 32; off >= 1; off >>= 1) m = fmaxf(m, __shfl_xor(m, off));
            float s = (m == 0.f) ? 1.f : m / 127.f;
            ow[l] = q4div(v0, s);
            if (l == 0) W2s[r] = s;
        } else {
            ow[l] = 0;
            if (l == 0) W2s[r] = 1.f;
        }
    }
}

// ---------------- fused MLP: quantize x -> GEMM1 -> relu+requant -> GEMM2 ----
// 256 threads (4 waves), BM=32. Phase 1 stages ALL 8 rows per wave into
// registers up front (25 f32x4 loads in flight -> 4x memory-level parallelism
// vs the load->reduce->load chain). Staging regs die before acc/h go live,
// so peak pressure ~120 < 128 (no spill).
__global__ __launch_bounds__(256, 4) void fused_mlp(
    const float* __restrict__ x,
    const int8_t* __restrict__ W1q, const float* __restrict__ W1s, const float* __restrict__ b1,
    const int8_t* __restrict__ W2q, const float* __restrict__ W2s, const float* __restrict__ b2,
    float* __restrict__ out)
{
    __shared__ __align__(16) int8_t xq[BM * XSTRIDE];   // 27136 B
    __shared__ __align__(16) int8_t hq[BM * HSTRIDE];   //  8704 B
    __shared__ float sxs[BM];
    __shared__ float hpart[4][BM];
    __shared__ float s2s[BM];
    __shared__ float b1s[256], w1ss[256];
    __shared__ float b2s[16], w2ss[16];

    const int t = threadIdx.x;
    const int l = t & 63;
    const int w = t >> 6;            // wave 0..3
    const int g = l >> 4;            // 16-lane group 0..3
    const int lr = l & 15;
    const size_t row0 = (size_t)blockIdx.x * BM;

    b1s[t] = b1[t];
    w1ss[t] = W1s[t];
    if (t < 16) { w2ss[t] = W2s[t]; b2s[t] = (t < 10) ? b2[t] : 0.f; }

    // ---- phase 1: batch-load 8 rows/wave, then absmax+quantize into LDS ----
    {
        const int rbase = w * 8;
        const float* xb = x + (row0 + rbase) * 784;

        // tail chunk first: lanes 0..31 hold row (l>>2), floats 768+4*(l&3)..
        f32x4 Rt = (f32x4){0.f, 0.f, 0.f, 0.f};
        if (l < 32) Rt = *(const f32x4*)(xb + (size_t)(l >> 2) * 784 + 4 * (192 + (l & 3)));

        f32x4 R[8][3];
        #pragma unroll
        for (int r = 0; r < 8; ++r) {
            const float* xr = xb + (size_t)r * 784;
            R[r][0] = *(const f32x4*)(xr + 4 * l);
            R[r][1] = *(const f32x4*)(xr + 4 * (l + 64));
            R[r][2] = *(const f32x4*)(xr + 4 * (l + 128));
        }

        #pragma unroll
        for (int r = 0; r < 8; ++r) {
            float m = fmaxf(fmaxf(max4abs(R[r][0]), max4abs(R[r][1])), max4abs(R[r][2]));
            if ((l >> 2) == r) m = fmaxf(m, max4abs(Rt));
            #pragma unroll
            for (int off = 32; off >= 1; off >>= 1) m = fmaxf(m, __shfl_xor(m, off));
            float s = (m == 0.f) ? 1.f : m / 127.f;
            float ri = 1.f / s;
            const int row = rbase + r;
            int* xw = (int*)(xq + row * XSTRIDE);
            xw[l] = q4ri(R[r][0], ri);
            xw[l + 64] = q4ri(R[r][1], ri);
            xw[l + 128] = q4ri(R[r][2], ri);
            if ((l >> 2) == r) xw[192 + (l & 3)] = q4ri(Rt, ri);
            if (l >= 16 && l < 32) xw[196 + (l - 16)] = 0;   // zero K-pad bytes 784..847
            if (l == 0) sxs[row] = s;
        }
    }
    __syncthreads();

    // ---- phase 2: layer-1 GEMM. wave w owns cols w*64..w*64+63, rows 0..31 ----
    i32x4 acc[2][4];
    #pragma unroll
    for (int mt = 0; mt < 2; ++mt)
        #pragma unroll
        for (int nt = 0; nt < 4; ++nt)
            acc[mt][nt] = (i32x4){0, 0, 0, 0};

    const int8_t* xbase = xq + lr * XSTRIDE + g * 16;
    const int8_t* wbase = W1q + (size_t)(w * 64 + lr) * 832 + g * 16;

    #pragma unroll
    for (int kk = 0; kk < 13; ++kk) {
        const int ko = kk * 64;
        i32x4 a[2], bv[4];
        #pragma unroll
        for (int mt = 0; mt < 2; ++mt) a[mt] = *(const i32x4*)(xbase + mt * 16 * XSTRIDE + ko);
        #pragma unroll
        for (int nt = 0; nt < 4; ++nt) bv[nt] = *(const i32x4*)(wbase + (size_t)nt * 16 * 832 + ko);
        #pragma unroll
        for (int mt = 0; mt < 2; ++mt)
            #pragma unroll
            for (int nt = 0; nt < 4; ++nt)
                acc[mt][nt] = __builtin_amdgcn_mfma_i32_16x16x64_i8(a[mt], bv[nt], acc[mt][nt], 0, 0, 0);
    }

    // ---- phase 3: dequant + bias + relu (exact: |acc| < 2^24) ----
    float h[2][4][4];   // [mt][reg][nt]
    #pragma unroll
    for (int mt = 0; mt < 2; ++mt)
        #pragma unroll
        for (int nt = 0; nt < 4; ++nt)
            #pragma unroll
            for (int r = 0; r < 4; ++r) {
                const int rowl = mt * 16 + g * 4 + r;
                const int coll = w * 64 + nt * 16 + lr;
                float v = sxs[rowl] * w1ss[coll] * (float)acc[mt][nt][r] + b1s[coll];
                h[mt][r][nt] = fmaxf(v, 0.f);
            }

    // ---- phase 4: per-row max of h (h>=0 so max == absmax) ----
    #pragma unroll
    for (int mt = 0; mt < 2; ++mt)
        #pragma unroll
        for (int r = 0; r < 4; ++r) {
            float m = fmaxf(fmaxf(h[mt][r][0], h[mt][r][1]), fmaxf(h[mt][r][2], h[mt][r][3]));
            m = fmaxf(m, __shfl_xor(m, 1));
            m = fmaxf(m, __shfl_xor(m, 2));
            m = fmaxf(m, __shfl_xor(m, 4));
            m = fmaxf(m, __shfl_xor(m, 8));
            if (lr == 0) hpart[w][mt * 16 + g * 4 + r] = m;
        }
    __syncthreads();

    // ---- phase 5: requantize h into LDS hq ----
    #pragma unroll
    for (int mt = 0; mt < 2; ++mt)
        #pragma unroll
        for (int r = 0; r < 4; ++r) {
            const int rowl = mt * 16 + g * 4 + r;
            float hm = fmaxf(fmaxf(hpart[0][rowl], hpart[1][rowl]),
                             fmaxf(hpart[2][rowl], hpart[3][rowl]));
            float s2 = (hm == 0.f) ? 1.f : hm / 127.f;
            float ri2 = 1.f / s2;
            if (w == 0 && lr == 0) s2s[rowl] = s2;
            #pragma unroll
            for (int nt = 0; nt < 4; ++nt) {
                float q = fminf(fmaxf(rintf(h[mt][r][nt] * ri2), -127.f), 127.f);
                hq[rowl * HSTRIDE + w * 64 + nt * 16 + lr] = (int8_t)(int)q;
            }
        }
    __syncthreads();

    // ---- phase 6+7: layer-2 GEMM (waves 0..1, 16 rows each) + epilogue ----
    if (w < 2) {
        i32x4 acc2 = (i32x4){0, 0, 0, 0};
        const int8_t* hbase = hq + (w * 16 + lr) * HSTRIDE + g * 16;
        const int8_t* w2base = W2q + lr * 256 + g * 16;
        #pragma unroll
        for (int kk = 0; kk < 4; ++kk) {
            i32x4 av = *(const i32x4*)(hbase + kk * 64);
            i32x4 bv = *(const i32x4*)(w2base + kk * 64);
            acc2 = __builtin_amdgcn_mfma_i32_16x16x64_i8(av, bv, acc2, 0, 0, 0);
        }
        if (lr < 10) {
            #pragma unroll
            for (int r = 0; r < 4; ++r) {
                const int rowl = w * 16 + g * 4 + r;
                float v = s2s[rowl] * w2ss[lr] * (float)acc2[r] + b2s[lr];
                out[(row0 + rowl) * 10 + lr] = v;
            }
        }
    }
}

extern "C" void kernel_launch(void* const* d_in, const int* in_sizes, int n_in,
                              void* d_out, int out_size, void* d_ws, size_t ws_size,
                              hipStream_t stream) {
    const float* x  = (const float*)d_in[0];
    const float* W1 = (const float*)d_in[1];
    const float* b1 = (const float*)d_in[2];
    const float* W2 = (const float*)d_in[3];
    const float* b2 = (const float*)d_in[4];
    float* out = (float*)d_out;

    int8_t* ws = (int8_t*)d_ws;
    int8_t* W1q = ws;                            // 256*832   = 212992 B
    float*  W1s = (float*)(ws + 212992);         // 1024 B
    int8_t* W2q = ws + 214016;                   // 4096 B
    float*  W2s = (float*)(ws + 218112);         // 64 B

    quantW<<<272, 64, 0, stream>>>(W1, W2, W1q, W1s, W2q, W2s);
    fused_mlp<<<2048, 256, 0, stream>>>(x, W1q, W1s, b1, W2q, W2s, b2, out);
}